// Round 1
// baseline (3701.585 us; speedup 1.0000x reference)
//
#include <hip/hip_runtime.h>
#include <math.h>

#define DEV __device__ __forceinline__

DEV float sigmoid_(float x){ return 1.f/(1.f+__expf(-x)); }
DEV float silu_(float x){ return x * sigmoid_(x); }
DEV float softplus_(float x){ return (x > 20.f) ? x : log1pf(__expf(x)); }
DEV float gelu_(float x){ return 0.5f*x*(1.f + erff(x*0.70710678118654752440f)); }

// ---------------- generic fp32 GEMM: C = act(A @ W^T + bias [+ R]) ----------------
// A: M x K (lda), W: N x K (row-major, ldw==K), C: M x N (ldc). ACT: 0 none, 1 softplus.
template<int ACT, int RES>
__global__ __launch_bounds__(256)
void gemm_k(const float* __restrict__ A, int lda,
            const float* __restrict__ W,
            const float* __restrict__ bias,
            const float* __restrict__ Rres,
            float* __restrict__ C, int ldc,
            int M, int N, int K)
{
  __shared__ float As[16][68];
  __shared__ float Ws[16][68];
  const int bm = blockIdx.x << 6;
  const int bn = blockIdx.y << 6;
  const int tid = threadIdx.x;
  const int tm0 = (tid >> 4) << 2;
  const int tn0 = (tid & 15) << 2;
  const int r   = tid >> 2;
  const int kk4 = (tid & 3) << 2;
  float acc[4][4] = {};
  for (int k0 = 0; k0 < K; k0 += 16) {
    const int gk = k0 + kk4;
    float4 va = make_float4(0.f,0.f,0.f,0.f);
    const int gr = bm + r;
    if (gr < M) {
      if (gk + 3 < K) va = *(const float4*)(A + (size_t)gr*lda + gk);
      else {
        va.x = (gk+0<K) ? A[(size_t)gr*lda+gk+0] : 0.f;
        va.y = (gk+1<K) ? A[(size_t)gr*lda+gk+1] : 0.f;
        va.z = (gk+2<K) ? A[(size_t)gr*lda+gk+2] : 0.f;
        va.w = (gk+3<K) ? A[(size_t)gr*lda+gk+3] : 0.f;
      }
    }
    As[kk4+0][r]=va.x; As[kk4+1][r]=va.y; As[kk4+2][r]=va.z; As[kk4+3][r]=va.w;
    float4 vw = make_float4(0.f,0.f,0.f,0.f);
    const int gc = bn + r;
    if (gc < N) {
      if (gk + 3 < K) vw = *(const float4*)(W + (size_t)gc*K + gk);
      else {
        vw.x = (gk+0<K) ? W[(size_t)gc*K+gk+0] : 0.f;
        vw.y = (gk+1<K) ? W[(size_t)gc*K+gk+1] : 0.f;
        vw.z = (gk+2<K) ? W[(size_t)gc*K+gk+2] : 0.f;
        vw.w = (gk+3<K) ? W[(size_t)gc*K+gk+3] : 0.f;
      }
    }
    Ws[kk4+0][r]=vw.x; Ws[kk4+1][r]=vw.y; Ws[kk4+2][r]=vw.z; Ws[kk4+3][r]=vw.w;
    __syncthreads();
    #pragma unroll
    for (int kk = 0; kk < 16; ++kk) {
      const float a0=As[kk][tm0+0], a1=As[kk][tm0+1], a2=As[kk][tm0+2], a3=As[kk][tm0+3];
      const float w0=Ws[kk][tn0+0], w1=Ws[kk][tn0+1], w2=Ws[kk][tn0+2], w3=Ws[kk][tn0+3];
      acc[0][0]+=a0*w0; acc[0][1]+=a0*w1; acc[0][2]+=a0*w2; acc[0][3]+=a0*w3;
      acc[1][0]+=a1*w0; acc[1][1]+=a1*w1; acc[1][2]+=a1*w2; acc[1][3]+=a1*w3;
      acc[2][0]+=a2*w0; acc[2][1]+=a2*w1; acc[2][2]+=a2*w2; acc[2][3]+=a2*w3;
      acc[3][0]+=a3*w0; acc[3][1]+=a3*w1; acc[3][2]+=a3*w2; acc[3][3]+=a3*w3;
    }
    __syncthreads();
  }
  #pragma unroll
  for (int i=0;i<4;i++){
    const int row = bm + tm0 + i;
    if (row >= M) continue;
    #pragma unroll
    for (int j=0;j<4;j++){
      const int col = bn + tn0 + j;
      if (col >= N) continue;
      float v = acc[i][j];
      if (bias) v += bias[col];
      if (RES)  v += Rres[(size_t)row*ldc + col];
      if (ACT == 1) v = softplus_(v);
      C[(size_t)row*ldc + col] = v;
    }
  }
}

// ---------------- patch conv: 16x16 stride-16 VALID conv, NCHW ----------------
// out xp[b][o][patch] with patch = ph*8+pw. block = (b, ph), thread = (o = tid&31, pw = tid>>5)
__global__ __launch_bounds__(256)
void patch_conv_k(const float* __restrict__ x, const float* __restrict__ w,
                  const float* __restrict__ bias, float* __restrict__ xp)
{
  const int bb = blockIdx.x >> 3;
  const int ph = blockIdx.x & 7;
  __shared__ float slab[2048];        // [16 rows][128 cols]
  __shared__ float wsh[256*33];       // [pos (kh*16+kw)][o] stride 33 (bank-conflict-free)
  const int tid = threadIdx.x;
  const int o  = tid & 31;
  const int pw = tid >> 5;
  float acc = 0.f;
  for (int c = 0; c < 32; ++c) {
    const float4* src = (const float4*)(x + ((size_t)(bb*32 + c)*128 + ph*16)*128);
    for (int i = tid; i < 512; i += 256) ((float4*)slab)[i] = src[i];
    for (int i = tid; i < 8192; i += 256) {
      const int o2 = i >> 8, pos = i & 255;
      wsh[pos*33 + o2] = w[((size_t)o2*32 + c)*256 + pos];
    }
    __syncthreads();
    const float* srow = slab + pw*16;
    #pragma unroll 4
    for (int kh = 0; kh < 16; ++kh) {
      #pragma unroll
      for (int kw = 0; kw < 16; ++kw)
        acc += srow[kh*128 + kw] * wsh[(kh*16 + kw)*33 + o];
    }
    __syncthreads();
  }
  xp[((size_t)bb*32 + o)*64 + ph*8 + pw] = acc + bias[o];
}

// ---------------- fused: x_proj assemble + gelu fuse + concat + layernorm ----------------
// one block per row (b*32+c), 256 threads; cat row = [x_patched(256) | x_fused(256) | x_proj(256)]
__global__ __launch_bounds__(256)
void fuse_ln_k(const float* __restrict__ xpat, const float* __restrict__ xprojbuf,
               const float* __restrict__ xfeat, const float* __restrict__ lnw,
               const float* __restrict__ lnb, const float* __restrict__ focusp,
               float* __restrict__ cat)
{
  const int row = blockIdx.x;
  const int t = threadIdx.x;
  const float focus = focusp[0];
  const float xp = xpat[(size_t)row*256 + t];
  const float pr = (t < 128) ? xfeat[(size_t)row*1280 + t] : xprojbuf[(size_t)row*256 + t];
  const float xf = gelu_(focus*pr + (2.f - focus)*xp);
  float s  = xp + xf + pr;
  float sq = xp*xp + xf*xf + pr*pr;
  __shared__ float rs[4], rq[4];
  const int lane = t & 63, wv = t >> 6;
  #pragma unroll
  for (int off = 32; off > 0; off >>= 1) {
    s  += __shfl_down(s,  off, 64);
    sq += __shfl_down(sq, off, 64);
  }
  if (lane == 0) { rs[wv] = s; rq[wv] = sq; }
  __syncthreads();
  const float S = rs[0]+rs[1]+rs[2]+rs[3];
  const float Q = rq[0]+rq[1]+rq[2]+rq[3];
  const float mu = S * (1.f/768.f);
  const float var = Q*(1.f/768.f) - mu*mu;
  const float rstd = rsqrtf(var + 1e-5f);
  const size_t ob = (size_t)row*768;
  cat[ob +        t] = (xp - mu)*rstd*lnw[      t] + lnb[      t];
  cat[ob + 256 +  t] = (xf - mu)*rstd*lnw[256 + t] + lnb[256 + t];
  cat[ob + 512 +  t] = (pr - mu)*rstd*lnw[512 + t] + lnb[512 + t];
}

// ---------------- prep: duplicate + flip into the 64-sequence batches ----------------
__global__ void prep_m1_k(const float* __restrict__ cat, float* __restrict__ X)
{
  const int idx = blockIdx.x*256 + threadIdx.x;   // 64*32*768
  if (idx >= 64*32*768) return;
  const int d = idx % 768;
  const int sl = idx / 768;
  const int l = sl & 31;
  const int s = sl >> 5;
  const int b = s & 31;
  const int ll = (s < 32) ? l : 31 - l;
  X[idx] = cat[((size_t)b*32 + ll)*768 + d];
}
__global__ void prep_m2_k(const float* __restrict__ cat, float* __restrict__ X)
{
  const int idx = blockIdx.x*256 + threadIdx.x;   // 64*768*32
  if (idx >= 64*768*32) return;
  const int c = idx & 31;
  const int sj = idx >> 5;
  const int j = sj % 768;
  const int s = sj / 768;
  const int b = (s < 32) ? s : s - 32;
  const int jj = (s < 32) ? j : 767 - j;
  X[idx] = cat[((size_t)b*32 + c)*768 + jj];
}

// ---------------- depthwise causal conv (k=4) + silu ----------------
__global__ void dwconv_silu_k(const float* __restrict__ xz, int ldxz,
                              const float* __restrict__ w, const float* __restrict__ b,
                              float* __restrict__ xc, int di, int L, int total)
{
  const int idx = blockIdx.x*256 + threadIdx.x;   // (s*L + l)*di + d
  if (idx >= total) return;
  const int d = idx % di;
  const int sl = idx / di;
  const int l = sl % L;
  float acc = b[d];
  const float* wd = w + d*4;
  #pragma unroll
  for (int k = 0; k < 4; ++k) {
    const int ll = l - 3 + k;
    if (ll >= 0) acc += xz[(size_t)(sl - 3 + k)*ldxz + d] * wd[k];
  }
  xc[idx] = silu_(acc);
}

// ---------------- selective scan (DS=16 states in registers) ----------------
// thread per (s,d); fuses dA/dBu compute, y = (scan + xc*D) * silu(z)
__global__ void scan_k(const float* __restrict__ delta, const float* __restrict__ xc,
                       const float* __restrict__ dbl, int lddbl, int droff,
                       const float* __restrict__ z, int ldz,
                       const float* __restrict__ A_log, const float* __restrict__ Dp,
                       float* __restrict__ Y, int di, int L, int total)
{
  const int idx = blockIdx.x*256 + threadIdx.x;
  if (idx >= total) return;
  const int d = idx % di;
  const int s = idx / di;
  float A[16], h[16];
  #pragma unroll
  for (int n = 0; n < 16; ++n) { A[n] = -__expf(A_log[d*16 + n]); h[n] = 0.f; }
  const float Dv = Dp[d];
  const size_t base = (size_t)s*L;
  for (int l = 0; l < L; ++l) {
    const size_t row = base + l;
    const float de  = delta[row*di + d];
    const float xcv = xc[row*di + d];
    const float du  = de * xcv;
    const float* bl = dbl + row*lddbl + droff;
    float y = 0.f;
    #pragma unroll
    for (int n = 0; n < 16; ++n) {
      const float dA = __expf(de * A[n]);
      h[n] = dA*h[n] + du*bl[n];
      y += h[n]*bl[16 + n];
    }
    const float zv = z[row*ldz + d];
    Y[row*di + d] = (y + xcv*Dv) * silu_(zv);
  }
}

// ---------------- combine + mean over l ----------------
// x3[b,j] = 1/32 * sum_i (x1p[b,i,j] + x1p[b+32,i,j] + x2p[b,j,i] + x2p[b+32,j,i])
__global__ __launch_bounds__(256)
void x3_k(const float* __restrict__ x1p, const float* __restrict__ x2p, float* __restrict__ x3)
{
  const int b = blockIdx.x;
  for (int j = threadIdx.x; j < 768; j += 256) {
    float s = 0.f;
    for (int i = 0; i < 32; ++i) {
      s += x1p[((size_t)b*32 + i)*768 + j] + x1p[((size_t)(b+32)*32 + i)*768 + j];
      s += x2p[((size_t)b*768 + j)*32 + i] + x2p[((size_t)(b+32)*768 + j)*32 + i];
    }
    x3[(size_t)b*768 + j] = s * (1.f/32.f);
  }
}

// ---------------- regression head ----------------
__global__ __launch_bounds__(512)
void head_k(const float* __restrict__ x3, const float* __restrict__ w1, const float* __restrict__ b1,
            const float* __restrict__ w2, const float* __restrict__ b2, float* __restrict__ out)
{
  const int b = blockIdx.x;
  const int t = threadIdx.x;
  __shared__ float xrow[768];
  for (int i = t; i < 768; i += 512) xrow[i] = x3[(size_t)b*768 + i];
  __syncthreads();
  float hv = 0.f;
  if (t < 384) {
    const float* wr = w1 + (size_t)t*768;
    float acc = b1[t];
    for (int d = 0; d < 768; ++d) acc += xrow[d]*wr[d];
    hv = acc * w2[t];
  }
  __shared__ float red[8];
  const int lane = t & 63, wv = t >> 6;
  #pragma unroll
  for (int off = 32; off > 0; off >>= 1) hv += __shfl_down(hv, off, 64);
  if (lane == 0) red[wv] = hv;
  __syncthreads();
  if (t == 0) {
    float s = b2[0];
    #pragma unroll
    for (int i = 0; i < 8; ++i) s += red[i];
    out[b] = s;
  }
}

extern "C" void kernel_launch(void* const* d_in, const int* in_sizes, int n_in,
                              void* d_out, int out_size, void* d_ws, size_t ws_size,
                              hipStream_t stream)
{
  (void)in_sizes; (void)n_in; (void)out_size;
  const float* x_cwt        = (const float*)d_in[0];
  const float* x_features   = (const float*)d_in[1];
  const float* patch_conv_w = (const float*)d_in[2];
  const float* patch_conv_b = (const float*)d_in[3];
  const float* patch_proj_w = (const float*)d_in[4];
  const float* patch_proj_b = (const float*)d_in[5];
  const float* feat_proj_w  = (const float*)d_in[6];
  const float* feat_proj_b  = (const float*)d_in[7];
  const float* ln_w         = (const float*)d_in[8];
  const float* ln_b         = (const float*)d_in[9];
  const float* focus        = (const float*)d_in[10];
  const float* reg_w1       = (const float*)d_in[11];
  const float* reg_b1       = (const float*)d_in[12];
  const float* reg_w2       = (const float*)d_in[13];
  const float* reg_b2       = (const float*)d_in[14];
  const float* m1w[9]; for (int i=0;i<9;i++) m1w[i] = (const float*)d_in[15+i];
  const float* m2w[9]; for (int i=0;i<9;i++) m2w[i] = (const float*)d_in[24+i];

  // workspace carve-up (floats)
  float* p = (float*)d_ws;
  size_t need = 0;
  auto alloc = [&](size_t n){ float* r = p; p += n; need += n; return r; };
  float* xp_buf    = alloc(65536);      // (32,32,64)  [b][o][patch]
  float* x_patched = alloc(262144);     // (1024,256)
  float* x_projb   = alloc(262144);     // (1024,256)  (cols 128..255 used)
  float* cat       = alloc(786432);     // (32,32,768)
  float* m1x       = alloc(1572864);    // (64,32,768)
  float* m2x       = alloc(1572864);    // (64,768,32)
  float* x3        = alloc(24576);      // (32,768)
  float* bxz       = alloc(6291456);    // shared m1/m2 xz
  float* bxc       = alloc(3145728);
  float* bdbl      = alloc(1671168);
  float* bdelta    = alloc(3145728);
  float* by        = alloc(3145728);
  if (ws_size < need * sizeof(float)) return;   // would corrupt; fail loudly via wrong output

  // ---- front-end ----
  patch_conv_k<<<256, 256, 0, stream>>>(x_cwt, patch_conv_w, patch_conv_b, xp_buf);
  gemm_k<0,0><<<dim3(16,4), 256, 0, stream>>>(xp_buf, 64, patch_proj_w, patch_proj_b,
                                              nullptr, x_patched, 256, 1024, 256, 64);
  gemm_k<0,0><<<dim3(16,2), 256, 0, stream>>>(x_features + 256, 1280, feat_proj_w, feat_proj_b,
                                              nullptr, x_projb + 128, 256, 1024, 128, 1024);
  fuse_ln_k<<<1024, 256, 0, stream>>>(x_patched, x_projb, x_features, ln_w, ln_b, focus, cat);
  prep_m1_k<<<6144, 256, 0, stream>>>(cat, m1x);
  prep_m2_k<<<6144, 256, 0, stream>>>(cat, m2x);

  // ---- m1: 2 layers on batched (64,32,768); di=1536, dr=48 ----
  for (int im = 0; im < 2; ++im) {
    const float* in_w   = m1w[0] + (size_t)im*3072*768;
    const float* conv_w = m1w[1] + (size_t)im*1536*4;
    const float* conv_b = m1w[2] + (size_t)im*1536;
    const float* xp_w   = m1w[3] + (size_t)im*80*1536;
    const float* dt_w   = m1w[4] + (size_t)im*1536*48;
    const float* dt_b   = m1w[5] + (size_t)im*1536;
    const float* A_log  = m1w[6] + (size_t)im*1536*16;
    const float* Dp     = m1w[7] + (size_t)im*1536;
    const float* out_w  = m1w[8] + (size_t)im*768*1536;
    gemm_k<0,0><<<dim3(32,48), 256, 0, stream>>>(m1x, 768, in_w, nullptr, nullptr,
                                                 bxz, 3072, 2048, 3072, 768);
    dwconv_silu_k<<<12288, 256, 0, stream>>>(bxz, 3072, conv_w, conv_b, bxc, 1536, 32, 2048*1536);
    gemm_k<0,0><<<dim3(32,2), 256, 0, stream>>>(bxc, 1536, xp_w, nullptr, nullptr,
                                                bdbl, 80, 2048, 80, 1536);
    gemm_k<1,0><<<dim3(32,24), 256, 0, stream>>>(bdbl, 80, dt_w, dt_b, nullptr,
                                                 bdelta, 1536, 2048, 1536, 48);
    scan_k<<<384, 256, 0, stream>>>(bdelta, bxc, bdbl, 80, 48, bxz + 1536, 3072,
                                    A_log, Dp, by, 1536, 32, 98304);
    gemm_k<0,1><<<dim3(32,12), 256, 0, stream>>>(by, 1536, out_w, nullptr, m1x,
                                                 m1x, 768, 2048, 768, 1536);
  }

  // ---- m2: 2 layers on batched (64,768,32); di=64, dr=2 ----
  for (int im = 0; im < 2; ++im) {
    const float* in_w   = m2w[0] + (size_t)im*128*32;
    const float* conv_w = m2w[1] + (size_t)im*64*4;
    const float* conv_b = m2w[2] + (size_t)im*64;
    const float* xp_w   = m2w[3] + (size_t)im*34*64;
    const float* dt_w   = m2w[4] + (size_t)im*64*2;
    const float* dt_b   = m2w[5] + (size_t)im*64;
    const float* A_log  = m2w[6] + (size_t)im*64*16;
    const float* Dp     = m2w[7] + (size_t)im*64;
    const float* out_w  = m2w[8] + (size_t)im*32*64;
    gemm_k<0,0><<<dim3(768,2), 256, 0, stream>>>(m2x, 32, in_w, nullptr, nullptr,
                                                 bxz, 128, 49152, 128, 32);
    dwconv_silu_k<<<12288, 256, 0, stream>>>(bxz, 128, conv_w, conv_b, bxc, 64, 768, 49152*64);
    gemm_k<0,0><<<dim3(768,1), 256, 0, stream>>>(bxc, 64, xp_w, nullptr, nullptr,
                                                 bdbl, 34, 49152, 34, 64);
    gemm_k<1,0><<<dim3(768,1), 256, 0, stream>>>(bdbl, 34, dt_w, dt_b, nullptr,
                                                 bdelta, 64, 49152, 64, 2);
    scan_k<<<16, 256, 0, stream>>>(bdelta, bxc, bdbl, 34, 2, bxz + 64, 128,
                                   A_log, Dp, by, 64, 768, 4096);
    gemm_k<0,1><<<dim3(768,1), 256, 0, stream>>>(by, 64, out_w, nullptr, m2x,
                                                 m2x, 32, 49152, 32, 64);
  }

  // ---- head ----
  x3_k<<<32, 256, 0, stream>>>(m1x, m2x, x3);
  head_k<<<32, 512, 0, stream>>>(x3, reg_w1, reg_b1, reg_w2, reg_b2, (float*)d_out);
}

// Round 2
// 1727.869 us; speedup vs baseline: 2.1423x; 2.1423x over previous
//
#include <hip/hip_runtime.h>
#include <math.h>

#define DEV __device__ __forceinline__

DEV float sigmoid_(float x){ return 1.f/(1.f+__expf(-x)); }
DEV float silu_(float x){ return x * sigmoid_(x); }
DEV float softplus_(float x){ return (x > 20.f) ? x : log1pf(__expf(x)); }
DEV float gelu_(float x){ return 0.5f*x*(1.f + erff(x*0.70710678118654752440f)); }

// ---------------- generic fp32 GEMM: C = act(A @ W^T + bias [+ R]) ----------------
// A: M x K (lda), W: N x K (row-major, ldw==K), C: M x N (ldc). ACT: 0 none, 1 softplus.
template<int ACT, int RES>
__global__ __launch_bounds__(256)
void gemm_k(const float* __restrict__ A, int lda,
            const float* __restrict__ W,
            const float* __restrict__ bias,
            const float* __restrict__ Rres,
            float* __restrict__ C, int ldc,
            int M, int N, int K)
{
  __shared__ float As[16][68];
  __shared__ float Ws[16][68];
  const int bm = blockIdx.x << 6;
  const int bn = blockIdx.y << 6;
  const int tid = threadIdx.x;
  const int tm0 = (tid >> 4) << 2;
  const int tn0 = (tid & 15) << 2;
  const int r   = tid >> 2;
  const int kk4 = (tid & 3) << 2;
  float acc[4][4] = {};
  for (int k0 = 0; k0 < K; k0 += 16) {
    const int gk = k0 + kk4;
    float4 va = make_float4(0.f,0.f,0.f,0.f);
    const int gr = bm + r;
    if (gr < M) {
      if (gk + 3 < K) va = *(const float4*)(A + (size_t)gr*lda + gk);
      else {
        va.x = (gk+0<K) ? A[(size_t)gr*lda+gk+0] : 0.f;
        va.y = (gk+1<K) ? A[(size_t)gr*lda+gk+1] : 0.f;
        va.z = (gk+2<K) ? A[(size_t)gr*lda+gk+2] : 0.f;
        va.w = (gk+3<K) ? A[(size_t)gr*lda+gk+3] : 0.f;
      }
    }
    As[kk4+0][r]=va.x; As[kk4+1][r]=va.y; As[kk4+2][r]=va.z; As[kk4+3][r]=va.w;
    float4 vw = make_float4(0.f,0.f,0.f,0.f);
    const int gc = bn + r;
    if (gc < N) {
      if (gk + 3 < K) vw = *(const float4*)(W + (size_t)gc*K + gk);
      else {
        vw.x = (gk+0<K) ? W[(size_t)gc*K+gk+0] : 0.f;
        vw.y = (gk+1<K) ? W[(size_t)gc*K+gk+1] : 0.f;
        vw.z = (gk+2<K) ? W[(size_t)gc*K+gk+2] : 0.f;
        vw.w = (gk+3<K) ? W[(size_t)gc*K+gk+3] : 0.f;
      }
    }
    Ws[kk4+0][r]=vw.x; Ws[kk4+1][r]=vw.y; Ws[kk4+2][r]=vw.z; Ws[kk4+3][r]=vw.w;
    __syncthreads();
    #pragma unroll
    for (int kk = 0; kk < 16; ++kk) {
      const float a0=As[kk][tm0+0], a1=As[kk][tm0+1], a2=As[kk][tm0+2], a3=As[kk][tm0+3];
      const float w0=Ws[kk][tn0+0], w1=Ws[kk][tn0+1], w2=Ws[kk][tn0+2], w3=Ws[kk][tn0+3];
      acc[0][0]+=a0*w0; acc[0][1]+=a0*w1; acc[0][2]+=a0*w2; acc[0][3]+=a0*w3;
      acc[1][0]+=a1*w0; acc[1][1]+=a1*w1; acc[1][2]+=a1*w2; acc[1][3]+=a1*w3;
      acc[2][0]+=a2*w0; acc[2][1]+=a2*w1; acc[2][2]+=a2*w2; acc[2][3]+=a2*w3;
      acc[3][0]+=a3*w0; acc[3][1]+=a3*w1; acc[3][2]+=a3*w2; acc[3][3]+=a3*w3;
    }
    __syncthreads();
  }
  #pragma unroll
  for (int i=0;i<4;i++){
    const int row = bm + tm0 + i;
    if (row >= M) continue;
    #pragma unroll
    for (int j=0;j<4;j++){
      const int col = bn + tn0 + j;
      if (col >= N) continue;
      float v = acc[i][j];
      if (bias) v += bias[col];
      if (RES)  v += Rres[(size_t)row*ldc + col];
      if (ACT == 1) v = softplus_(v);
      C[(size_t)row*ldc + col] = v;
    }
  }
}

// ---------------- patch conv: 16x16 stride-16 VALID conv, NCHW ----------------
__global__ __launch_bounds__(256)
void patch_conv_k(const float* __restrict__ x, const float* __restrict__ w,
                  const float* __restrict__ bias, float* __restrict__ xp)
{
  const int bb = blockIdx.x >> 3;
  const int ph = blockIdx.x & 7;
  __shared__ float slab[2048];        // [16 rows][128 cols]
  __shared__ float wsh[256*33];       // [pos][o] stride 33
  const int tid = threadIdx.x;
  const int o  = tid & 31;
  const int pw = tid >> 5;
  float acc = 0.f;
  for (int c = 0; c < 32; ++c) {
    const float4* src = (const float4*)(x + ((size_t)(bb*32 + c)*128 + ph*16)*128);
    for (int i = tid; i < 512; i += 256) ((float4*)slab)[i] = src[i];
    for (int i = tid; i < 8192; i += 256) {
      const int o2 = i >> 8, pos = i & 255;
      wsh[pos*33 + o2] = w[((size_t)o2*32 + c)*256 + pos];
    }
    __syncthreads();
    const float* srow = slab + pw*16;
    #pragma unroll 4
    for (int kh = 0; kh < 16; ++kh) {
      #pragma unroll
      for (int kw = 0; kw < 16; ++kw)
        acc += srow[kh*128 + kw] * wsh[(kh*16 + kw)*33 + o];
    }
    __syncthreads();
  }
  xp[((size_t)bb*32 + o)*64 + ph*8 + pw] = acc + bias[o];
}

// ---------------- fused: x_proj assemble + gelu fuse + concat + layernorm ----------------
__global__ __launch_bounds__(256)
void fuse_ln_k(const float* __restrict__ xpat, const float* __restrict__ xprojbuf,
               const float* __restrict__ xfeat, const float* __restrict__ lnw,
               const float* __restrict__ lnb, const float* __restrict__ focusp,
               float* __restrict__ cat)
{
  const int row = blockIdx.x;
  const int t = threadIdx.x;
  const float focus = focusp[0];
  const float xp = xpat[(size_t)row*256 + t];
  const float pr = (t < 128) ? xfeat[(size_t)row*1280 + t] : xprojbuf[(size_t)row*256 + t];
  const float xf = gelu_(focus*pr + (2.f - focus)*xp);
  float s  = xp + xf + pr;
  float sq = xp*xp + xf*xf + pr*pr;
  __shared__ float rs[4], rq[4];
  const int lane = t & 63, wv = t >> 6;
  #pragma unroll
  for (int off = 32; off > 0; off >>= 1) {
    s  += __shfl_down(s,  off, 64);
    sq += __shfl_down(sq, off, 64);
  }
  if (lane == 0) { rs[wv] = s; rq[wv] = sq; }
  __syncthreads();
  const float S = rs[0]+rs[1]+rs[2]+rs[3];
  const float Q = rq[0]+rq[1]+rq[2]+rq[3];
  const float mu = S * (1.f/768.f);
  const float var = Q*(1.f/768.f) - mu*mu;
  const float rstd = rsqrtf(var + 1e-5f);
  const size_t ob = (size_t)row*768;
  cat[ob +        t] = (xp - mu)*rstd*lnw[      t] + lnb[      t];
  cat[ob + 256 +  t] = (xf - mu)*rstd*lnw[256 + t] + lnb[256 + t];
  cat[ob + 512 +  t] = (pr - mu)*rstd*lnw[512 + t] + lnb[512 + t];
}

// ---------------- prep: duplicate + flip into the 64-sequence batches ----------------
__global__ void prep_m1_k(const float* __restrict__ cat, float* __restrict__ X)
{
  const int idx = blockIdx.x*256 + threadIdx.x;   // 64*32*768
  if (idx >= 64*32*768) return;
  const int d = idx % 768;
  const int sl = idx / 768;
  const int l = sl & 31;
  const int s = sl >> 5;
  const int b = s & 31;
  const int ll = (s < 32) ? l : 31 - l;
  X[idx] = cat[((size_t)b*32 + ll)*768 + d];
}
__global__ void prep_m2_k(const float* __restrict__ cat, float* __restrict__ X)
{
  const int idx = blockIdx.x*256 + threadIdx.x;   // 64*768*32
  if (idx >= 64*768*32) return;
  const int c = idx & 31;
  const int sj = idx >> 5;
  const int j = sj % 768;
  const int s = sj / 768;
  const int b = (s < 32) ? s : s - 32;
  const int jj = (s < 32) ? j : 767 - j;
  X[idx] = cat[((size_t)b*32 + c)*768 + jj];
}

// ---------------- depthwise causal conv (k=4) + silu ----------------
__global__ void dwconv_silu_k(const float* __restrict__ xz, int ldxz,
                              const float* __restrict__ w, const float* __restrict__ b,
                              float* __restrict__ xc, int di, int L, int total)
{
  const int idx = blockIdx.x*256 + threadIdx.x;
  if (idx >= total) return;
  const int d = idx % di;
  const int sl = idx / di;
  const int l = sl % L;
  float acc = b[d];
  const float* wd = w + d*4;
  #pragma unroll
  for (int k = 0; k < 4; ++k) {
    const int ll = l - 3 + k;
    if (ll >= 0) acc += xz[(size_t)(sl - 3 + k)*ldxz + d] * wd[k];
  }
  xc[idx] = silu_(acc);
}

// ---------------- m1 selective scan (L=32, plenty of threads) ----------------
__global__ void scan_k(const float* __restrict__ delta, const float* __restrict__ xc,
                       const float* __restrict__ dbl, int lddbl, int droff,
                       const float* __restrict__ z, int ldz,
                       const float* __restrict__ A_log, const float* __restrict__ Dp,
                       float* __restrict__ Y, int di, int L, int total)
{
  const int idx = blockIdx.x*256 + threadIdx.x;
  if (idx >= total) return;
  const int d = idx % di;
  const int s = idx / di;
  float A[16], h[16];
  #pragma unroll
  for (int n = 0; n < 16; ++n) { A[n] = -__expf(A_log[d*16 + n]); h[n] = 0.f; }
  const float Dv = Dp[d];
  const size_t base = (size_t)s*L;
  for (int l = 0; l < L; ++l) {
    const size_t row = base + l;
    const float de  = delta[row*di + d];
    const float xcv = xc[row*di + d];
    const float du  = de * xcv;
    const float* bl = dbl + row*lddbl + droff;
    float y = 0.f;
    #pragma unroll
    for (int n = 0; n < 16; ++n) {
      const float dA = __expf(de * A[n]);
      h[n] = dA*h[n] + du*bl[n];
      y += h[n]*bl[16 + n];
    }
    const float zv = z[row*ldz + d];
    Y[row*di + d] = (y + xcv*Dv) * silu_(zv);
  }
}

// ---------------- m2 chunked scan: L=768 -> NC2 chunks of LC2 ----------------
// m2 constants: di=64, lddbl=34, droff=2 (B at +2, C at +18), ldz=128, L=768
#define NC2 16
#define LC2 48

// partA: local scan per chunk with h0=0; emit h_end[16] and sum(delta)
__global__ __launch_bounds__(256)
void scan2_partA(const float* __restrict__ delta, const float* __restrict__ xc,
                 const float* __restrict__ dbl, const float* __restrict__ A_log,
                 float* __restrict__ Hend, float* __restrict__ sde_buf)
{
  const int t = blockIdx.x*256 + threadIdx.x;     // 64*64*NC2 = 65536
  if (t >= 64*64*NC2) return;
  const int d = t & 63;
  const int c = (t >> 6) & (NC2-1);
  const int s = t >> 10;
  float A[16], h[16];
  #pragma unroll
  for (int n = 0; n < 16; ++n) { A[n] = -__expf(A_log[d*16 + n]); h[n] = 0.f; }
  float sde = 0.f;
  const size_t row0 = (size_t)s*768 + c*LC2;
  for (int l = 0; l < LC2; ++l) {
    const size_t row = row0 + l;
    const float de  = delta[row*64 + d];
    const float xcv = xc[row*64 + d];
    const float du  = de * xcv;
    const float* bl = dbl + row*34 + 2;
    sde += de;
    #pragma unroll
    for (int n = 0; n < 16; ++n)
      h[n] = __expf(de*A[n])*h[n] + du*bl[n];
  }
  float* hp = Hend + (size_t)t*16;
  #pragma unroll
  for (int n = 0; n < 16; ++n) hp[n] = h[n];
  sde_buf[t] = sde;
}

// carry: serial over chunks; overwrite Hend[c] with the INCOMING state H_in[c]
__global__ void scan2_carry(const float* __restrict__ A_log,
                            float* __restrict__ Hend, const float* __restrict__ sde_buf)
{
  const int t = blockIdx.x*256 + threadIdx.x;     // 64*64 = 4096
  if (t >= 4096) return;
  const int d = t & 63;
  const int s = t >> 6;
  float A[16], H[16];
  #pragma unroll
  for (int n = 0; n < 16; ++n) { A[n] = -__expf(A_log[d*16 + n]); H[n] = 0.f; }
  for (int c = 0; c < NC2; ++c) {
    const size_t off = ((size_t)(s*NC2 + c)*64 + d)*16;
    const float sde = sde_buf[(s*NC2 + c)*64 + d];
    #pragma unroll
    for (int n = 0; n < 16; ++n) {
      const float he = Hend[off + n];
      Hend[off + n] = H[n];                       // becomes H_in for chunk c
      H[n] = __expf(sde*A[n])*H[n] + he;
    }
  }
}

// partC: rerun local scan seeded with H_in; produce fused outputs
__global__ __launch_bounds__(256)
void scan2_partC(const float* __restrict__ delta, const float* __restrict__ xc,
                 const float* __restrict__ dbl, const float* __restrict__ z,
                 const float* __restrict__ A_log, const float* __restrict__ Dp,
                 const float* __restrict__ Hin, float* __restrict__ Y)
{
  const int t = blockIdx.x*256 + threadIdx.x;
  if (t >= 64*64*NC2) return;
  const int d = t & 63;
  const int c = (t >> 6) & (NC2-1);
  const int s = t >> 10;
  float A[16], h[16];
  #pragma unroll
  for (int n = 0; n < 16; ++n) {
    A[n] = -__expf(A_log[d*16 + n]);
    h[n] = Hin[(size_t)t*16 + n];
  }
  const float Dv = Dp[d];
  const size_t row0 = (size_t)s*768 + c*LC2;
  for (int l = 0; l < LC2; ++l) {
    const size_t row = row0 + l;
    const float de  = delta[row*64 + d];
    const float xcv = xc[row*64 + d];
    const float du  = de * xcv;
    const float* bl = dbl + row*34 + 2;
    float y = 0.f;
    #pragma unroll
    for (int n = 0; n < 16; ++n) {
      const float dA = __expf(de*A[n]);
      h[n] = dA*h[n] + du*bl[n];
      y += h[n]*bl[16 + n];
    }
    const float zv = z[row*128 + d];
    Y[row*64 + d] = (y + xcv*Dv) * silu_(zv);
  }
}

// ---------------- combine + mean over l ----------------
__global__ __launch_bounds__(256)
void x3_k(const float* __restrict__ x1p, const float* __restrict__ x2p, float* __restrict__ x3)
{
  const int b = blockIdx.x;
  for (int j = threadIdx.x; j < 768; j += 256) {
    float s = 0.f;
    for (int i = 0; i < 32; ++i) {
      s += x1p[((size_t)b*32 + i)*768 + j] + x1p[((size_t)(b+32)*32 + i)*768 + j];
      s += x2p[((size_t)b*768 + j)*32 + i] + x2p[((size_t)(b+32)*768 + j)*32 + i];
    }
    x3[(size_t)b*768 + j] = s * (1.f/32.f);
  }
}

// ---------------- regression head ----------------
__global__ __launch_bounds__(512)
void head_k(const float* __restrict__ x3, const float* __restrict__ w1, const float* __restrict__ b1,
            const float* __restrict__ w2, const float* __restrict__ b2, float* __restrict__ out)
{
  const int b = blockIdx.x;
  const int t = threadIdx.x;
  __shared__ float xrow[768];
  for (int i = t; i < 768; i += 512) xrow[i] = x3[(size_t)b*768 + i];
  __syncthreads();
  float hv = 0.f;
  if (t < 384) {
    const float* wr = w1 + (size_t)t*768;
    float acc = b1[t];
    for (int d = 0; d < 768; ++d) acc += xrow[d]*wr[d];
    hv = acc * w2[t];
  }
  __shared__ float red[8];
  const int lane = t & 63, wv = t >> 6;
  #pragma unroll
  for (int off = 32; off > 0; off >>= 1) hv += __shfl_down(hv, off, 64);
  if (lane == 0) red[wv] = hv;
  __syncthreads();
  if (t == 0) {
    float s = b2[0];
    #pragma unroll
    for (int i = 0; i < 8; ++i) s += red[i];
    out[b] = s;
  }
}

extern "C" void kernel_launch(void* const* d_in, const int* in_sizes, int n_in,
                              void* d_out, int out_size, void* d_ws, size_t ws_size,
                              hipStream_t stream)
{
  (void)in_sizes; (void)n_in; (void)out_size;
  const float* x_cwt        = (const float*)d_in[0];
  const float* x_features   = (const float*)d_in[1];
  const float* patch_conv_w = (const float*)d_in[2];
  const float* patch_conv_b = (const float*)d_in[3];
  const float* patch_proj_w = (const float*)d_in[4];
  const float* patch_proj_b = (const float*)d_in[5];
  const float* feat_proj_w  = (const float*)d_in[6];
  const float* feat_proj_b  = (const float*)d_in[7];
  const float* ln_w         = (const float*)d_in[8];
  const float* ln_b         = (const float*)d_in[9];
  const float* focus        = (const float*)d_in[10];
  const float* reg_w1       = (const float*)d_in[11];
  const float* reg_b1       = (const float*)d_in[12];
  const float* reg_w2       = (const float*)d_in[13];
  const float* reg_b2       = (const float*)d_in[14];
  const float* m1w[9]; for (int i=0;i<9;i++) m1w[i] = (const float*)d_in[15+i];
  const float* m2w[9]; for (int i=0;i<9;i++) m2w[i] = (const float*)d_in[24+i];

  // workspace carve-up (floats)
  float* p = (float*)d_ws;
  size_t need = 0;
  auto alloc = [&](size_t n){ float* r = p; p += n; need += n; return r; };
  float* xp_buf    = alloc(65536);      // (32,32,64)   dead after patch_proj
  float* x_patched = alloc(262144);     // (1024,256)   dead after fuse_ln
  float* x_projb   = alloc(262144);     // (1024,256)   dead after fuse_ln
  float* cat       = alloc(786432);     // (32,32,768)  dead after preps
  float* m1x       = alloc(1572864);    // (64,32,768)
  float* m2x       = alloc(1572864);    // (64,768,32)
  float* x3        = alloc(24576);      // (32,768)
  float* bxz       = alloc(6291456);
  float* bxc       = alloc(3145728);
  float* bdbl      = alloc(1671168);
  float* bdelta    = alloc(3145728);
  float* by        = alloc(3145728);
  if (ws_size < need * sizeof(float)) return;
  // overlay for the m2 chunked scan: front-end buffers are dead by then
  float* sHend = (float*)d_ws;          // 64*NC2*64*16 = 1,048,576 floats
  float* sSde  = sHend + 64*NC2*64*16;  // 65,536 floats  (total 1,114,112 <= 1,376,256 dead)

  // ---- front-end ----
  patch_conv_k<<<256, 256, 0, stream>>>(x_cwt, patch_conv_w, patch_conv_b, xp_buf);
  gemm_k<0,0><<<dim3(16,4), 256, 0, stream>>>(xp_buf, 64, patch_proj_w, patch_proj_b,
                                              nullptr, x_patched, 256, 1024, 256, 64);
  gemm_k<0,0><<<dim3(16,2), 256, 0, stream>>>(x_features + 256, 1280, feat_proj_w, feat_proj_b,
                                              nullptr, x_projb + 128, 256, 1024, 128, 1024);
  fuse_ln_k<<<1024, 256, 0, stream>>>(x_patched, x_projb, x_features, ln_w, ln_b, focus, cat);
  prep_m1_k<<<6144, 256, 0, stream>>>(cat, m1x);
  prep_m2_k<<<6144, 256, 0, stream>>>(cat, m2x);

  // ---- m1: 2 layers on batched (64,32,768); di=1536, dr=48 ----
  for (int im = 0; im < 2; ++im) {
    const float* in_w   = m1w[0] + (size_t)im*3072*768;
    const float* conv_w = m1w[1] + (size_t)im*1536*4;
    const float* conv_b = m1w[2] + (size_t)im*1536;
    const float* xp_w   = m1w[3] + (size_t)im*80*1536;
    const float* dt_w   = m1w[4] + (size_t)im*1536*48;
    const float* dt_b   = m1w[5] + (size_t)im*1536;
    const float* A_log  = m1w[6] + (size_t)im*1536*16;
    const float* Dp     = m1w[7] + (size_t)im*1536;
    const float* out_w  = m1w[8] + (size_t)im*768*1536;
    gemm_k<0,0><<<dim3(32,48), 256, 0, stream>>>(m1x, 768, in_w, nullptr, nullptr,
                                                 bxz, 3072, 2048, 3072, 768);
    dwconv_silu_k<<<12288, 256, 0, stream>>>(bxz, 3072, conv_w, conv_b, bxc, 1536, 32, 2048*1536);
    gemm_k<0,0><<<dim3(32,2), 256, 0, stream>>>(bxc, 1536, xp_w, nullptr, nullptr,
                                                bdbl, 80, 2048, 80, 1536);
    gemm_k<1,0><<<dim3(32,24), 256, 0, stream>>>(bdbl, 80, dt_w, dt_b, nullptr,
                                                 bdelta, 1536, 2048, 1536, 48);
    scan_k<<<384, 256, 0, stream>>>(bdelta, bxc, bdbl, 80, 48, bxz + 1536, 3072,
                                    A_log, Dp, by, 1536, 32, 98304);
    gemm_k<0,1><<<dim3(32,12), 256, 0, stream>>>(by, 1536, out_w, nullptr, m1x,
                                                 m1x, 768, 2048, 768, 1536);
  }

  // ---- m2: 2 layers on batched (64,768,32); di=64, dr=2 ----
  for (int im = 0; im < 2; ++im) {
    const float* in_w   = m2w[0] + (size_t)im*128*32;
    const float* conv_w = m2w[1] + (size_t)im*64*4;
    const float* conv_b = m2w[2] + (size_t)im*64;
    const float* xp_w   = m2w[3] + (size_t)im*34*64;
    const float* dt_w   = m2w[4] + (size_t)im*64*2;
    const float* dt_b   = m2w[5] + (size_t)im*64;
    const float* A_log  = m2w[6] + (size_t)im*64*16;
    const float* Dp     = m2w[7] + (size_t)im*64;
    const float* out_w  = m2w[8] + (size_t)im*32*64;
    gemm_k<0,0><<<dim3(768,2), 256, 0, stream>>>(m2x, 32, in_w, nullptr, nullptr,
                                                 bxz, 128, 49152, 128, 32);
    dwconv_silu_k<<<12288, 256, 0, stream>>>(bxz, 128, conv_w, conv_b, bxc, 64, 768, 49152*64);
    gemm_k<0,0><<<dim3(768,1), 256, 0, stream>>>(bxc, 64, xp_w, nullptr, nullptr,
                                                 bdbl, 34, 49152, 34, 64);
    gemm_k<1,0><<<dim3(768,1), 256, 0, stream>>>(bdbl, 34, dt_w, dt_b, nullptr,
                                                 bdelta, 64, 49152, 64, 2);
    scan2_partA<<<256, 256, 0, stream>>>(bdelta, bxc, bdbl, A_log, sHend, sSde);
    scan2_carry<<<16, 256, 0, stream>>>(A_log, sHend, sSde);
    scan2_partC<<<256, 256, 0, stream>>>(bdelta, bxc, bdbl, bxz + 64, A_log, Dp, sHend, by);
    gemm_k<0,1><<<dim3(768,1), 256, 0, stream>>>(by, 64, out_w, nullptr, m2x,
                                                 m2x, 32, 49152, 32, 64);
  }

  // ---- head ----
  x3_k<<<32, 256, 0, stream>>>(m1x, m2x, x3);
  head_k<<<32, 512, 0, stream>>>(x3, reg_w1, reg_b1, reg_w2, reg_b2, (float*)d_out);
}

// Round 3
// 1642.420 us; speedup vs baseline: 2.2537x; 1.0520x over previous
//
#include <hip/hip_runtime.h>
#include <math.h>

#define DEV __device__ __forceinline__

DEV float sigmoid_(float x){ return 1.f/(1.f+__expf(-x)); }
DEV float silu_(float x){ return x * sigmoid_(x); }
DEV float softplus_(float x){ return (x > 20.f) ? x : log1pf(__expf(x)); }
DEV float gelu_(float x){ return 0.5f*x*(1.f + erff(x*0.70710678118654752440f)); }

typedef __attribute__((ext_vector_type(8))) short short8v;   // 8 bf16 (bit pattern)
typedef __attribute__((ext_vector_type(4))) float floatx4;

// ---------------- generic fp32 GEMM (kept for small/odd shapes) ----------------
template<int ACT, int RES>
__global__ __launch_bounds__(256)
void gemm_k(const float* __restrict__ A, int lda,
            const float* __restrict__ W,
            const float* __restrict__ bias,
            const float* __restrict__ Rres,
            float* __restrict__ C, int ldc,
            int M, int N, int K)
{
  __shared__ float As[16][68];
  __shared__ float Ws[16][68];
  const int bm = blockIdx.x << 6;
  const int bn = blockIdx.y << 6;
  const int tid = threadIdx.x;
  const int tm0 = (tid >> 4) << 2;
  const int tn0 = (tid & 15) << 2;
  const int r   = tid >> 2;
  const int kk4 = (tid & 3) << 2;
  float acc[4][4] = {};
  for (int k0 = 0; k0 < K; k0 += 16) {
    const int gk = k0 + kk4;
    float4 va = make_float4(0.f,0.f,0.f,0.f);
    const int gr = bm + r;
    if (gr < M) {
      if (gk + 3 < K) va = *(const float4*)(A + (size_t)gr*lda + gk);
      else {
        va.x = (gk+0<K) ? A[(size_t)gr*lda+gk+0] : 0.f;
        va.y = (gk+1<K) ? A[(size_t)gr*lda+gk+1] : 0.f;
        va.z = (gk+2<K) ? A[(size_t)gr*lda+gk+2] : 0.f;
        va.w = (gk+3<K) ? A[(size_t)gr*lda+gk+3] : 0.f;
      }
    }
    As[kk4+0][r]=va.x; As[kk4+1][r]=va.y; As[kk4+2][r]=va.z; As[kk4+3][r]=va.w;
    float4 vw = make_float4(0.f,0.f,0.f,0.f);
    const int gc = bn + r;
    if (gc < N) {
      if (gk + 3 < K) vw = *(const float4*)(W + (size_t)gc*K + gk);
      else {
        vw.x = (gk+0<K) ? W[(size_t)gc*K+gk+0] : 0.f;
        vw.y = (gk+1<K) ? W[(size_t)gc*K+gk+1] : 0.f;
        vw.z = (gk+2<K) ? W[(size_t)gc*K+gk+2] : 0.f;
        vw.w = (gk+3<K) ? W[(size_t)gc*K+gk+3] : 0.f;
      }
    }
    Ws[kk4+0][r]=vw.x; Ws[kk4+1][r]=vw.y; Ws[kk4+2][r]=vw.z; Ws[kk4+3][r]=vw.w;
    __syncthreads();
    #pragma unroll
    for (int kk = 0; kk < 16; ++kk) {
      const float a0=As[kk][tm0+0], a1=As[kk][tm0+1], a2=As[kk][tm0+2], a3=As[kk][tm0+3];
      const float w0=Ws[kk][tn0+0], w1=Ws[kk][tn0+1], w2=Ws[kk][tn0+2], w3=Ws[kk][tn0+3];
      acc[0][0]+=a0*w0; acc[0][1]+=a0*w1; acc[0][2]+=a0*w2; acc[0][3]+=a0*w3;
      acc[1][0]+=a1*w0; acc[1][1]+=a1*w1; acc[1][2]+=a1*w2; acc[1][3]+=a1*w3;
      acc[2][0]+=a2*w0; acc[2][1]+=a2*w1; acc[2][2]+=a2*w2; acc[2][3]+=a2*w3;
      acc[3][0]+=a3*w0; acc[3][1]+=a3*w1; acc[3][2]+=a3*w2; acc[3][3]+=a3*w3;
    }
    __syncthreads();
  }
  #pragma unroll
  for (int i=0;i<4;i++){
    const int row = bm + tm0 + i;
    if (row >= M) continue;
    #pragma unroll
    for (int j=0;j<4;j++){
      const int col = bn + tn0 + j;
      if (col >= N) continue;
      float v = acc[i][j];
      if (bias) v += bias[col];
      if (RES)  v += Rres[(size_t)row*ldc + col];
      if (ACT == 1) v = softplus_(v);
      C[(size_t)row*ldc + col] = v;
    }
  }
}

// ---------------- triple-split conversion: fp32 R x C -> bf16 R x KP ----------------
// row layout: [hi(C) | P2(C) | P3(C) | zeros(KP-3C)]
// modeA=1: P2=hi, P3=lo   (A operand)     modeA=0: P2=lo, P3=hi   (W operand)
__global__ void cvt3_k(const float* __restrict__ X, int ldx, short* __restrict__ Y,
                       int C, int KP, int modeA, int total)
{
  const int idx = blockIdx.x*256 + threadIdx.x;
  if (idx >= total) return;          // total = R*KP
  const int c3 = idx % KP;
  const int r  = idx / KP;
  short out = 0;
  if (c3 < 3*C) {
    const int part = c3 / C;
    const int c = c3 - part*C;
    const float x = X[(size_t)r*ldx + c];
    const unsigned u = __float_as_uint(x);
    const unsigned hi_bits = (u + 0x7FFFu + ((u >> 16) & 1u)) >> 16;
    const bool want_lo = modeA ? (part == 2) : (part == 1);
    if (want_lo) {
      const float lo_f = x - __uint_as_float(hi_bits << 16);
      const unsigned ul = __float_as_uint(lo_f);
      out = (short)((ul + 0x7FFFu + ((ul >> 16) & 1u)) >> 16);
    } else {
      out = (short)hi_bits;
    }
  }
  Y[(size_t)r*KP + c3] = out;
}

// ---------------- bf16 MFMA GEMM: C = act(A3 @ W3^T + bias [+ R]) ----------------
// A3: M x K3 bf16, W3: N x K3 bf16, C: M x N fp32 (ldc == N). M%128==0, N%128==0, K3%32==0.
template<int ACT, int RES, int BIAS>
__global__ __launch_bounds__(256)
void gemm3_mfma_k(const short* __restrict__ A3, const short* __restrict__ W3,
                  const float* __restrict__ bias, const float* __restrict__ Rres,
                  float* __restrict__ C, int M, int N, int K3)
{
  __shared__ short As[128][40];     // 80 B rows -> 2-way (free) bank pattern
  __shared__ short Ws[128][40];
  const int bm = blockIdx.x << 7;
  const int bn = blockIdx.y << 7;
  const int tid = threadIdx.x;
  const int lane = tid & 63;
  const int wv = tid >> 6;
  const int wr = (wv >> 1) << 6;    // wave row offset within tile
  const int wc = (wv & 1) << 6;     // wave col offset
  const int frow = lane & 15;
  const int fk   = lane >> 4;       // k-chunk 0..3 (8 bf16 each)
  const int srow = tid >> 1;        // staging: row per thread-pair
  const int shalf = (tid & 1) << 4; // 0 / 16 bf16

  floatx4 acc[4][4] = {};
  const short* gA = A3 + (size_t)(bm + srow)*K3 + shalf;
  const short* gW = W3 + (size_t)(bn + srow)*K3 + shalf;

  for (int k0 = 0; k0 < K3; k0 += 32) {
    short8v va0 = *(const short8v*)(gA + k0);
    short8v va1 = *(const short8v*)(gA + k0 + 8);
    short8v vw0 = *(const short8v*)(gW + k0);
    short8v vw1 = *(const short8v*)(gW + k0 + 8);
    __syncthreads();
    *(short8v*)&As[srow][shalf]     = va0;
    *(short8v*)&As[srow][shalf + 8] = va1;
    *(short8v*)&Ws[srow][shalf]     = vw0;
    *(short8v*)&Ws[srow][shalf + 8] = vw1;
    __syncthreads();
    short8v af[4], bf[4];
    #pragma unroll
    for (int mf = 0; mf < 4; ++mf)
      af[mf] = *(const short8v*)&As[wr + mf*16 + frow][fk*8];
    #pragma unroll
    for (int nf = 0; nf < 4; ++nf)
      bf[nf] = *(const short8v*)&Ws[wc + nf*16 + frow][fk*8];
    #pragma unroll
    for (int mf = 0; mf < 4; ++mf)
      #pragma unroll
      for (int nf = 0; nf < 4; ++nf)
        acc[mf][nf] = __builtin_amdgcn_mfma_f32_16x16x32_bf16(af[mf], bf[nf], acc[mf][nf], 0, 0, 0);
  }

  #pragma unroll
  for (int mf = 0; mf < 4; ++mf) {
    #pragma unroll
    for (int nf = 0; nf < 4; ++nf) {
      const int col = bn + wc + nf*16 + (lane & 15);
      #pragma unroll
      for (int r = 0; r < 4; ++r) {
        const int row = bm + wr + mf*16 + (lane >> 4)*4 + r;
        float v = acc[mf][nf][r];
        if (BIAS) v += bias[col];
        if (RES)  v += Rres[(size_t)row*N + col];
        if (ACT == 1) v = softplus_(v);
        C[(size_t)row*N + col] = v;
      }
    }
  }
}

// ---------------- patch conv: 16x16 stride-16 VALID conv, register-tiled ----------------
// block=(b,ph) 256 blocks; thread: og=tid&7 (4 o's), pg=(tid>>3)&3 (2 pw's), ks=tid>>5 (2 kh rows)
__global__ __launch_bounds__(256)
void patch_conv_k(const float* __restrict__ x, const float* __restrict__ w,
                  const float* __restrict__ bias, float* __restrict__ xp)
{
  const int bb = blockIdx.x >> 3;
  const int ph = blockIdx.x & 7;
  __shared__ float slab2[8*260];      // [pw][kh*16+kw] pad 4
  __shared__ float wsh[256*36];       // [pos][o] stride 36 (16B-aligned float4 rows)
  const int tid = threadIdx.x;
  const int og = tid & 7;
  const int pg = (tid >> 3) & 3;
  const int ks = tid >> 5;
  float acc[4][2] = {};
  for (int c = 0; c < 32; ++c) {
    const float4* src = (const float4*)(x + ((size_t)(bb*32 + c)*128 + ph*16)*128);
    for (int i = tid; i < 512; i += 256) {
      float4 v = src[i];
      const int r = i >> 5;            // image row 0..15
      const int c4 = (i & 31) << 2;    // col 0..124
      *(float4*)&slab2[(c4 >> 4)*260 + r*16 + (c4 & 15)] = v;
    }
    for (int i = tid; i < 8192; i += 256) {
      const int o2 = i >> 8, pos = i & 255;
      wsh[pos*36 + o2] = w[((size_t)o2*32 + c)*256 + pos];
    }
    __syncthreads();
    #pragma unroll
    for (int khi = 0; khi < 2; ++khi) {
      const int kh = ks*2 + khi;
      #pragma unroll
      for (int kw4 = 0; kw4 < 16; kw4 += 4) {
        const float4 s0 = *(const float4*)&slab2[(pg*2+0)*260 + kh*16 + kw4];
        const float4 s1 = *(const float4*)&slab2[(pg*2+1)*260 + kh*16 + kw4];
        #pragma unroll
        for (int q = 0; q < 4; ++q) {
          const float4 wvq = *(const float4*)&wsh[(kh*16 + kw4 + q)*36 + og*4];
          const float sv0 = (&s0.x)[q], sv1 = (&s1.x)[q];
          acc[0][0] += wvq.x*sv0; acc[0][1] += wvq.x*sv1;
          acc[1][0] += wvq.y*sv0; acc[1][1] += wvq.y*sv1;
          acc[2][0] += wvq.z*sv0; acc[2][1] += wvq.z*sv1;
          acc[3][0] += wvq.w*sv0; acc[3][1] += wvq.w*sv1;
        }
      }
    }
    __syncthreads();
  }
  // reduce across the 8 kh-splits (reuse wsh)
  #pragma unroll
  for (int j = 0; j < 4; ++j)
    #pragma unroll
    for (int i = 0; i < 2; ++i)
      wsh[tid*8 + j*2 + i] = acc[j][i];
  __syncthreads();
  if (ks == 0) {
    const int pos = tid & 31;
    #pragma unroll
    for (int j = 0; j < 4; ++j) {
      const int o = og*4 + j;
      #pragma unroll
      for (int i = 0; i < 2; ++i) {
        float s = 0.f;
        #pragma unroll
        for (int k2 = 0; k2 < 8; ++k2) s += wsh[(k2*32 + pos)*8 + j*2 + i];
        xp[((size_t)bb*32 + o)*64 + ph*8 + pg*2 + i] = s + bias[o];
      }
    }
  }
}

// ---------------- fused: x_proj assemble + gelu fuse + concat + layernorm ----------------
__global__ __launch_bounds__(256)
void fuse_ln_k(const float* __restrict__ xpat, const float* __restrict__ xprojbuf,
               const float* __restrict__ xfeat, const float* __restrict__ lnw,
               const float* __restrict__ lnb, const float* __restrict__ focusp,
               float* __restrict__ cat)
{
  const int row = blockIdx.x;
  const int t = threadIdx.x;
  const float focus = focusp[0];
  const float xp = xpat[(size_t)row*256 + t];
  const float pr = (t < 128) ? xfeat[(size_t)row*1280 + t] : xprojbuf[(size_t)row*256 + t];
  const float xf = gelu_(focus*pr + (2.f - focus)*xp);
  float s  = xp + xf + pr;
  float sq = xp*xp + xf*xf + pr*pr;
  __shared__ float rs[4], rq[4];
  const int lane = t & 63, wv = t >> 6;
  #pragma unroll
  for (int off = 32; off > 0; off >>= 1) {
    s  += __shfl_down(s,  off, 64);
    sq += __shfl_down(sq, off, 64);
  }
  if (lane == 0) { rs[wv] = s; rq[wv] = sq; }
  __syncthreads();
  const float S = rs[0]+rs[1]+rs[2]+rs[3];
  const float Q = rq[0]+rq[1]+rq[2]+rq[3];
  const float mu = S * (1.f/768.f);
  const float var = Q*(1.f/768.f) - mu*mu;
  const float rstd = rsqrtf(var + 1e-5f);
  const size_t ob = (size_t)row*768;
  cat[ob +        t] = (xp - mu)*rstd*lnw[      t] + lnb[      t];
  cat[ob + 256 +  t] = (xf - mu)*rstd*lnw[256 + t] + lnb[256 + t];
  cat[ob + 512 +  t] = (pr - mu)*rstd*lnw[512 + t] + lnb[512 + t];
}

// ---------------- prep: duplicate + flip into the 64-sequence batches ----------------
__global__ void prep_m1_k(const float* __restrict__ cat, float* __restrict__ X)
{
  const int idx = blockIdx.x*256 + threadIdx.x;
  if (idx >= 64*32*768) return;
  const int d = idx % 768;
  const int sl = idx / 768;
  const int l = sl & 31;
  const int s = sl >> 5;
  const int b = s & 31;
  const int ll = (s < 32) ? l : 31 - l;
  X[idx] = cat[((size_t)b*32 + ll)*768 + d];
}
__global__ void prep_m2_k(const float* __restrict__ cat, float* __restrict__ X)
{
  const int idx = blockIdx.x*256 + threadIdx.x;
  if (idx >= 64*768*32) return;
  const int c = idx & 31;
  const int sj = idx >> 5;
  const int j = sj % 768;
  const int s = sj / 768;
  const int b = (s < 32) ? s : s - 32;
  const int jj = (s < 32) ? j : 767 - j;
  X[idx] = cat[((size_t)b*32 + c)*768 + jj];
}

// ---------------- depthwise causal conv (k=4) + silu ----------------
__global__ void dwconv_silu_k(const float* __restrict__ xz, int ldxz,
                              const float* __restrict__ w, const float* __restrict__ b,
                              float* __restrict__ xc, int di, int L, int total)
{
  const int idx = blockIdx.x*256 + threadIdx.x;
  if (idx >= total) return;
  const int d = idx % di;
  const int sl = idx / di;
  const int l = sl % L;
  float acc = b[d];
  const float* wd = w + d*4;
  #pragma unroll
  for (int k = 0; k < 4; ++k) {
    const int ll = l - 3 + k;
    if (ll >= 0) acc += xz[(size_t)(sl - 3 + k)*ldxz + d] * wd[k];
  }
  xc[idx] = silu_(acc);
}

// ---------------- m1 selective scan (L=32) ----------------
__global__ void scan_k(const float* __restrict__ delta, const float* __restrict__ xc,
                       const float* __restrict__ dbl, int lddbl, int droff,
                       const float* __restrict__ z, int ldz,
                       const float* __restrict__ A_log, const float* __restrict__ Dp,
                       float* __restrict__ Y, int di, int L, int total)
{
  const int idx = blockIdx.x*256 + threadIdx.x;
  if (idx >= total) return;
  const int d = idx % di;
  const int s = idx / di;
  float A[16], h[16];
  #pragma unroll
  for (int n = 0; n < 16; ++n) { A[n] = -__expf(A_log[d*16 + n]); h[n] = 0.f; }
  const float Dv = Dp[d];
  const size_t base = (size_t)s*L;
  for (int l = 0; l < L; ++l) {
    const size_t row = base + l;
    const float de  = delta[row*di + d];
    const float xcv = xc[row*di + d];
    const float du  = de * xcv;
    const float* bl = dbl + row*lddbl + droff;
    float y = 0.f;
    #pragma unroll
    for (int n = 0; n < 16; ++n) {
      const float dA = __expf(de * A[n]);
      h[n] = dA*h[n] + du*bl[n];
      y += h[n]*bl[16 + n];
    }
    const float zv = z[row*ldz + d];
    Y[row*di + d] = (y + xcv*Dv) * silu_(zv);
  }
}

// ---------------- m2 chunked scan ----------------
#define NC2 16
#define LC2 48

__global__ __launch_bounds__(256)
void scan2_partA(const float* __restrict__ delta, const float* __restrict__ xc,
                 const float* __restrict__ dbl, const float* __restrict__ A_log,
                 float* __restrict__ Hend, float* __restrict__ sde_buf)
{
  const int t = blockIdx.x*256 + threadIdx.x;
  if (t >= 64*64*NC2) return;
  const int d = t & 63;
  const int c = (t >> 6) & (NC2-1);
  const int s = t >> 10;
  float A[16], h[16];
  #pragma unroll
  for (int n = 0; n < 16; ++n) { A[n] = -__expf(A_log[d*16 + n]); h[n] = 0.f; }
  float sde = 0.f;
  const size_t row0 = (size_t)s*768 + c*LC2;
  for (int l = 0; l < LC2; ++l) {
    const size_t row = row0 + l;
    const float de  = delta[row*64 + d];
    const float xcv = xc[row*64 + d];
    const float du  = de * xcv;
    const float* bl = dbl + row*34 + 2;
    sde += de;
    #pragma unroll
    for (int n = 0; n < 16; ++n)
      h[n] = __expf(de*A[n])*h[n] + du*bl[n];
  }
  float* hp = Hend + (size_t)t*16;
  #pragma unroll
  for (int n = 0; n < 16; ++n) hp[n] = h[n];
  sde_buf[t] = sde;
}

__global__ void scan2_carry(const float* __restrict__ A_log,
                            float* __restrict__ Hend, const float* __restrict__ sde_buf)
{
  const int t = blockIdx.x*256 + threadIdx.x;
  if (t >= 4096) return;
  const int d = t & 63;
  const int s = t >> 6;
  float A[16], H[16];
  #pragma unroll
  for (int n = 0; n < 16; ++n) { A[n] = -__expf(A_log[d*16 + n]); H[n] = 0.f; }
  for (int c = 0; c < NC2; ++c) {
    const size_t off = ((size_t)(s*NC2 + c)*64 + d)*16;
    const float sde = sde_buf[(s*NC2 + c)*64 + d];
    #pragma unroll
    for (int n = 0; n < 16; ++n) {
      const float he = Hend[off + n];
      Hend[off + n] = H[n];
      H[n] = __expf(sde*A[n])*H[n] + he;
    }
  }
}

__global__ __launch_bounds__(256)
void scan2_partC(const float* __restrict__ delta, const float* __restrict__ xc,
                 const float* __restrict__ dbl, const float* __restrict__ z,
                 const float* __restrict__ A_log, const float* __restrict__ Dp,
                 const float* __restrict__ Hin, float* __restrict__ Y)
{
  const int t = blockIdx.x*256 + threadIdx.x;
  if (t >= 64*64*NC2) return;
  const int d = t & 63;
  const int c = (t >> 6) & (NC2-1);
  const int s = t >> 10;
  float A[16], h[16];
  #pragma unroll
  for (int n = 0; n < 16; ++n) {
    A[n] = -__expf(A_log[d*16 + n]);
    h[n] = Hin[(size_t)t*16 + n];
  }
  const float Dv = Dp[d];
  const size_t row0 = (size_t)s*768 + c*LC2;
  for (int l = 0; l < LC2; ++l) {
    const size_t row = row0 + l;
    const float de  = delta[row*64 + d];
    const float xcv = xc[row*64 + d];
    const float du  = de * xcv;
    const float* bl = dbl + row*34 + 2;
    float y = 0.f;
    #pragma unroll
    for (int n = 0; n < 16; ++n) {
      const float dA = __expf(de*A[n]);
      h[n] = dA*h[n] + du*bl[n];
      y += h[n]*bl[16 + n];
    }
    const float zv = z[row*128 + d];
    Y[row*64 + d] = (y + xcv*Dv) * silu_(zv);
  }
}

// ---------------- combine + mean over l ----------------
__global__ __launch_bounds__(256)
void x3_k(const float* __restrict__ x1p, const float* __restrict__ x2p, float* __restrict__ x3)
{
  const int b = blockIdx.x;
  for (int j = threadIdx.x; j < 768; j += 256) {
    float s = 0.f;
    for (int i = 0; i < 32; ++i) {
      s += x1p[((size_t)b*32 + i)*768 + j] + x1p[((size_t)(b+32)*32 + i)*768 + j];
      s += x2p[((size_t)b*768 + j)*32 + i] + x2p[((size_t)(b+32)*768 + j)*32 + i];
    }
    x3[(size_t)b*768 + j] = s * (1.f/32.f);
  }
}

// ---------------- regression head ----------------
__global__ __launch_bounds__(512)
void head_k(const float* __restrict__ x3, const float* __restrict__ w1, const float* __restrict__ b1,
            const float* __restrict__ w2, const float* __restrict__ b2, float* __restrict__ out)
{
  const int b = blockIdx.x;
  const int t = threadIdx.x;
  __shared__ float xrow[768];
  for (int i = t; i < 768; i += 512) xrow[i] = x3[(size_t)b*768 + i];
  __syncthreads();
  float hv = 0.f;
  if (t < 384) {
    const float* wr = w1 + (size_t)t*768;
    float acc = b1[t];
    for (int d = 0; d < 768; ++d) acc += xrow[d]*wr[d];
    hv = acc * w2[t];
  }
  __shared__ float red[8];
  const int lane = t & 63, wv = t >> 6;
  #pragma unroll
  for (int off = 32; off > 0; off >>= 1) hv += __shfl_down(hv, off, 64);
  if (lane == 0) red[wv] = hv;
  __syncthreads();
  if (t == 0) {
    float s = b2[0];
    #pragma unroll
    for (int i = 0; i < 8; ++i) s += red[i];
    out[b] = s;
  }
}

extern "C" void kernel_launch(void* const* d_in, const int* in_sizes, int n_in,
                              void* d_out, int out_size, void* d_ws, size_t ws_size,
                              hipStream_t stream)
{
  (void)in_sizes; (void)n_in; (void)out_size;
  const float* x_cwt        = (const float*)d_in[0];
  const float* x_features   = (const float*)d_in[1];
  const float* patch_conv_w = (const float*)d_in[2];
  const float* patch_conv_b = (const float*)d_in[3];
  const float* patch_proj_w = (const float*)d_in[4];
  const float* patch_proj_b = (const float*)d_in[5];
  const float* feat_proj_w  = (const float*)d_in[6];
  const float* feat_proj_b  = (const float*)d_in[7];
  const float* ln_w         = (const float*)d_in[8];
  const float* ln_b         = (const float*)d_in[9];
  const float* focus        = (const float*)d_in[10];
  const float* reg_w1       = (const float*)d_in[11];
  const float* reg_b1       = (const float*)d_in[12];
  const float* reg_w2       = (const float*)d_in[13];
  const float* reg_b2       = (const float*)d_in[14];
  const float* m1w[9]; for (int i=0;i<9;i++) m1w[i] = (const float*)d_in[15+i];
  const float* m2w[9]; for (int i=0;i<9;i++) m2w[i] = (const float*)d_in[24+i];

  // workspace carve-up (floats) — unchanged footprint
  float* p = (float*)d_ws;
  size_t need = 0;
  auto alloc = [&](size_t n){ float* r = p; p += n; need += n; return r; };
  float* xp_buf    = alloc(65536);
  float* x_patched = alloc(262144);
  float* x_projb   = alloc(262144);
  float* cat       = alloc(786432);
  float* m1x       = alloc(1572864);    // (64,32,768)
  float* m2x       = alloc(1572864);    // (64,768,32)
  float* x3        = alloc(24576);
  float* bxz       = alloc(6291456);    // (2048,3072) m1 / (49152,128) m2
  float* bxc       = alloc(3145728);
  float* bdbl      = alloc(1671168);
  float* bdelta    = alloc(3145728);
  float* by        = alloc(3145728);
  if (ws_size < need * sizeof(float)) return;
  // m2-scan overlays (front-end region dead by then)
  float* sHend = (float*)d_ws;
  float* sSde  = sHend + 64*NC2*64*16;
  // m1 MFMA operand overlays (all regions dead at time of use; traced in comments)
  short* A3i  = (short*)bxc;            // 2048x2304 bf16 = 9.4 MB  (bxc free pre-dwconv)
  short* W3i  = (short*)bdelta;         // 3072x2304 bf16 = 14.2 MB (spans bdelta+by, both free)
  short* A3dt = (short*)by;             // 2048x160
  short* W3dt = (short*)by + 400000;    // 1536x160
  short* A3o  = (short*)bxz;            // 2048x4608 = 18.9 MB (z dead after scan)
  short* W3o  = (short*)bxc;            // 768x4608  = 7.1 MB  (xc dead after scan)

  // ---- front-end ----
  patch_conv_k<<<256, 256, 0, stream>>>(x_cwt, patch_conv_w, patch_conv_b, xp_buf);
  gemm_k<0,0><<<dim3(16,4), 256, 0, stream>>>(xp_buf, 64, patch_proj_w, patch_proj_b,
                                              nullptr, x_patched, 256, 1024, 256, 64);
  gemm_k<0,0><<<dim3(16,2), 256, 0, stream>>>(x_features + 256, 1280, feat_proj_w, feat_proj_b,
                                              nullptr, x_projb + 128, 256, 1024, 128, 1024);
  fuse_ln_k<<<1024, 256, 0, stream>>>(x_patched, x_projb, x_features, ln_w, ln_b, focus, cat);
  prep_m1_k<<<6144, 256, 0, stream>>>(cat, m1x);

  // ---- m1: 2 layers on batched (64,32,768); di=1536, dr=48 ----
  for (int im = 0; im < 2; ++im) {
    const float* in_w   = m1w[0] + (size_t)im*3072*768;
    const float* conv_w = m1w[1] + (size_t)im*1536*4;
    const float* conv_b = m1w[2] + (size_t)im*1536;
    const float* xp_w   = m1w[3] + (size_t)im*80*1536;
    const float* dt_w   = m1w[4] + (size_t)im*1536*48;
    const float* dt_b   = m1w[5] + (size_t)im*1536;
    const float* A_log  = m1w[6] + (size_t)im*1536*16;
    const float* Dp     = m1w[7] + (size_t)im*1536;
    const float* out_w  = m1w[8] + (size_t)im*768*1536;
    // in-proj: (2048x768) @ (3072x768)^T -> bxz, via triple-split MFMA (K3=2304)
    cvt3_k<<<(2048*2304+255)/256, 256, 0, stream>>>(m1x, 768, A3i, 768, 2304, 1, 2048*2304);
    cvt3_k<<<(3072*2304+255)/256, 256, 0, stream>>>(in_w, 768, W3i, 768, 2304, 0, 3072*2304);
    gemm3_mfma_k<0,0,0><<<dim3(16,24), 256, 0, stream>>>(A3i, W3i, nullptr, nullptr,
                                                         bxz, 2048, 3072, 2304);
    dwconv_silu_k<<<12288, 256, 0, stream>>>(bxz, 3072, conv_w, conv_b, bxc, 1536, 32, 2048*1536);
    gemm_k<0,0><<<dim3(32,2), 256, 0, stream>>>(bxc, 1536, xp_w, nullptr, nullptr,
                                                bdbl, 80, 2048, 80, 1536);
    // delta: (2048x48) @ (1536x48)^T + b, softplus; K3=144 padded to 160
    cvt3_k<<<(2048*160+255)/256, 256, 0, stream>>>(bdbl, 80, A3dt, 48, 160, 1, 2048*160);
    cvt3_k<<<(1536*160+255)/256, 256, 0, stream>>>(dt_w, 48, W3dt, 48, 160, 0, 1536*160);
    gemm3_mfma_k<1,0,1><<<dim3(16,12), 256, 0, stream>>>(A3dt, W3dt, dt_b, nullptr,
                                                         bdelta, 2048, 1536, 160);
    scan_k<<<384, 256, 0, stream>>>(bdelta, bxc, bdbl, 80, 48, bxz + 1536, 3072,
                                    A_log, Dp, by, 1536, 32, 98304);
    // out-proj: (2048x1536) @ (768x1536)^T + residual -> m1x; K3=4608
    cvt3_k<<<(2048*4608+255)/256, 256, 0, stream>>>(by, 1536, A3o, 1536, 4608, 1, 2048*4608);
    cvt3_k<<<(768*4608+255)/256, 256, 0, stream>>>(out_w, 1536, W3o, 1536, 4608, 0, 768*4608);
    gemm3_mfma_k<0,1,0><<<dim3(16,6), 256, 0, stream>>>(A3o, W3o, nullptr, m1x,
                                                        m1x, 2048, 768, 4608);
  }

  // ---- m2 prep (cat still alive) ----
  prep_m2_k<<<6144, 256, 0, stream>>>(cat, m2x);

  // ---- m2: 2 layers on batched (64,768,32); di=64, dr=2 ----
  for (int im = 0; im < 2; ++im) {
    const float* in_w   = m2w[0] + (size_t)im*128*32;
    const float* conv_w = m2w[1] + (size_t)im*64*4;
    const float* conv_b = m2w[2] + (size_t)im*64;
    const float* xp_w   = m2w[3] + (size_t)im*34*64;
    const float* dt_w   = m2w[4] + (size_t)im*64*2;
    const float* dt_b   = m2w[5] + (size_t)im*64;
    const float* A_log  = m2w[6] + (size_t)im*64*16;
    const float* Dp     = m2w[7] + (size_t)im*64;
    const float* out_w  = m2w[8] + (size_t)im*32*64;
    gemm_k<0,0><<<dim3(768,2), 256, 0, stream>>>(m2x, 32, in_w, nullptr, nullptr,
                                                 bxz, 128, 49152, 128, 32);
    dwconv_silu_k<<<12288, 256, 0, stream>>>(bxz, 128, conv_w, conv_b, bxc, 64, 768, 49152*64);
    gemm_k<0,0><<<dim3(768,1), 256, 0, stream>>>(bxc, 64, xp_w, nullptr, nullptr,
                                                 bdbl, 34, 49152, 34, 64);
    gemm_k<1,0><<<dim3(768,1), 256, 0, stream>>>(bdbl, 34, dt_w, dt_b, nullptr,
                                                 bdelta, 64, 49152, 64, 2);
    scan2_partA<<<256, 256, 0, stream>>>(bdelta, bxc, bdbl, A_log, sHend, sSde);
    scan2_carry<<<16, 256, 0, stream>>>(A_log, sHend, sSde);
    scan2_partC<<<256, 256, 0, stream>>>(bdelta, bxc, bdbl, bxz + 64, A_log, Dp, sHend, by);
    gemm_k<0,1><<<dim3(768,1), 256, 0, stream>>>(by, 64, out_w, nullptr, m2x,
                                                 m2x, 32, 49152, 32, 64);
  }

  // ---- head ----
  x3_k<<<32, 256, 0, stream>>>(m1x, m2x, x3);
  head_k<<<32, 512, 0, stream>>>(x3, reg_w1, reg_b1, reg_w2, reg_b2, (float*)d_out);
}